// Round 1
// baseline (133.139 us; speedup 1.0000x reference)
//
#include <hip/hip_runtime.h>
#include <hip/hip_bf16.h>
#include <cstdint>
#include <cstddef>

#define N_PTS 4096
#define DIM   2048
#define BM 128
#define BN 128
#define BK 32

typedef __bf16 bf16x8 __attribute__((ext_vector_type(8)));
typedef float  f32x4  __attribute__((ext_vector_type(4)));
typedef unsigned short u16x8 __attribute__((ext_vector_type(8)));

__device__ __forceinline__ unsigned short f32_to_bf16_rne(float f) {
  unsigned u = __float_as_uint(f);
  u += 0x7fffu + ((u >> 16) & 1u);
  return (unsigned short)(u >> 16);
}

__device__ __forceinline__ void load_lds16(const void* g, void* l) {
  __builtin_amdgcn_global_load_lds(
      (const __attribute__((address_space(1))) void*)g,
      (__attribute__((address_space(3))) void*)l, 16, 0, 0);
}

// ---------------- prep: fp32 -> bf16 + exact fp32 row sum-of-squares ----------------
__global__ __launch_bounds__(256) void prep_kernel(const float* __restrict__ X,
                                                   unsigned short* __restrict__ Xb,
                                                   float* __restrict__ sq) {
  const int row = blockIdx.x;
  const int t = threadIdx.x;
  const float4* xr = (const float4*)(X + (size_t)row * DIM);
  float4 v0 = xr[t * 2 + 0];
  float4 v1 = xr[t * 2 + 1];
  float s = v0.x * v0.x + v0.y * v0.y + v0.z * v0.z + v0.w * v0.w
          + v1.x * v1.x + v1.y * v1.y + v1.z * v1.z + v1.w * v1.w;
  u16x8 o;
  o[0] = f32_to_bf16_rne(v0.x); o[1] = f32_to_bf16_rne(v0.y);
  o[2] = f32_to_bf16_rne(v0.z); o[3] = f32_to_bf16_rne(v0.w);
  o[4] = f32_to_bf16_rne(v1.x); o[5] = f32_to_bf16_rne(v1.y);
  o[6] = f32_to_bf16_rne(v1.z); o[7] = f32_to_bf16_rne(v1.w);
  *(u16x8*)(Xb + (size_t)row * DIM + t * 8) = o;

  #pragma unroll
  for (int off = 32; off > 0; off >>= 1) s += __shfl_down(s, off, 64);
  __shared__ float wsum[4];
  const int lane = t & 63, w = t >> 6;
  if (lane == 0) wsum[w] = s;
  __syncthreads();
  if (t == 0) sq[row] = wsum[0] + wsum[1] + wsum[2] + wsum[3];
}

// ---------------- init far/near arrays ----------------
__global__ void init_kernel(unsigned* __restrict__ far_bits,
                            unsigned* __restrict__ near_bits) {
  int i = blockIdx.x * 256 + threadIdx.x;
  if (i < N_PTS) {
    far_bits[i]  = 0u;           // 0.0f
    near_bits[i] = 0x7f800000u;  // +inf
  }
}

// ---------------- main fused pairwise-dist + row reduce ----------------
__global__ __launch_bounds__(256) void pairdist_kernel(
    const unsigned short* __restrict__ Xb, const float* __restrict__ sq,
    const int* __restrict__ tgt, unsigned* __restrict__ far_bits,
    unsigned* __restrict__ near_bits) {
  __shared__ unsigned short As[BM * BK];  // 8 KiB
  __shared__ unsigned short Bs[BN * BK];  // 8 KiB
  __shared__ float sq_r[BM], sq_c[BN];
  __shared__ int   t_r[BM],  t_c[BN];

  const int tid  = threadIdx.x;
  const int lane = tid & 63;
  const int w    = tid >> 6;        // wave 0..3
  const int wr   = w >> 1;          // wave row 0..1
  const int wc   = w & 1;           // wave col 0..1
  const int i0   = blockIdx.y * BM;
  const int j0   = blockIdx.x * BN;

  if (tid < 128) { sq_r[tid] = sq[i0 + tid]; t_r[tid] = tgt[i0 + tid]; }
  else { int c = tid - 128; sq_c[c] = sq[j0 + c]; t_c[c] = tgt[j0 + c]; }

  f32x4 acc[4][4] = {};

  // staging geometry: per global_load_lds instr, a wave covers 16 rows x 64B
  const int srow = lane >> 2;          // row within 16-row chunk
  const int scol = (lane & 3) * 8;     // bf16 elems within BK row
  const int fr   = lane & 15;          // fragment row/col index
  const int kc   = (lane >> 4) * 8;    // fragment k offset (contiguous 8)

  for (int k0 = 0; k0 < DIM; k0 += BK) {
    const unsigned short* gA0 = Xb + (size_t)(i0 + w * 16 + srow) * DIM + k0 + scol;
    const unsigned short* gB0 = Xb + (size_t)(j0 + w * 16 + srow) * DIM + k0 + scol;
    load_lds16(gA0,            &As[(w * 16) * BK]);
    load_lds16(gA0 + 64 * DIM, &As[(64 + w * 16) * BK]);
    load_lds16(gB0,            &Bs[(w * 16) * BK]);
    load_lds16(gB0 + 64 * DIM, &Bs[(64 + w * 16) * BK]);
    __syncthreads();

    bf16x8 a[4], b[4];
    #pragma unroll
    for (int m = 0; m < 4; m++)
      a[m] = *(const bf16x8*)&As[(wr * 64 + m * 16 + fr) * BK + kc];
    #pragma unroll
    for (int n = 0; n < 4; n++)
      b[n] = *(const bf16x8*)&Bs[(wc * 64 + n * 16 + fr) * BK + kc];
    #pragma unroll
    for (int m = 0; m < 4; m++)
      #pragma unroll
      for (int n = 0; n < 4; n++)
        acc[m][n] = __builtin_amdgcn_mfma_f32_16x16x32_bf16(a[m], b[n], acc[m][n], 0, 0, 0);
    __syncthreads();
  }

  // epilogue: dist + masked per-row far/near
  const int hi = lane >> 4;
  #pragma unroll
  for (int m = 0; m < 4; m++) {
    #pragma unroll
    for (int r = 0; r < 4; r++) {
      const int rl = wr * 64 + m * 16 + hi * 4 + r;
      const int gi = i0 + rl;
      const float sqr = sq_r[rl];
      const int   trw = t_r[rl];
      float fmx = 0.0f;
      float nmn = __builtin_inff();
      #pragma unroll
      for (int n = 0; n < 4; n++) {
        const int cl = wc * 64 + n * 16 + fr;
        const int gj = j0 + cl;
        const float g  = acc[m][n][r];
        float d2 = sqr + sq_c[cl] - 2.0f * g;
        float d  = sqrtf(fmaxf(d2, 1e-12f));
        if (trw == t_c[cl]) {
          fmx = fmaxf(fmx, d);
          if (gi != gj) nmn = fminf(nmn, d);
        }
      }
      #pragma unroll
      for (int s = 1; s < 16; s <<= 1) {
        fmx = fmaxf(fmx, __shfl_xor(fmx, s, 64));
        nmn = fminf(nmn, __shfl_xor(nmn, s, 64));
      }
      if ((lane & 15) == 0) {
        atomicMax(&far_bits[gi],  __float_as_uint(fmx));
        atomicMin(&near_bits[gi], __float_as_uint(nmn));
      }
    }
  }
}

// ---------------- final deterministic reduction ----------------
__global__ __launch_bounds__(256) void finalize_kernel(
    const unsigned* __restrict__ far_bits, const unsigned* __restrict__ near_bits,
    float* __restrict__ out) {
  __shared__ float red[256];
  const int t = threadIdx.x;
  float s = 0.0f;
  for (int i = t; i < N_PTS; i += 256) {
    float fa = __uint_as_float(far_bits[i]);
    float ne = __uint_as_float(near_bits[i]);
    s += fmaxf(fa - ne, 0.0f);   // near=+inf -> -inf -> 0
  }
  red[t] = s;
  __syncthreads();
  for (int off = 128; off > 0; off >>= 1) {
    if (t < off) red[t] += red[t + off];
    __syncthreads();
  }
  if (t == 0) out[0] = red[0] / (float)N_PTS;
}

extern "C" void kernel_launch(void* const* d_in, const int* in_sizes, int n_in,
                              void* d_out, int out_size, void* d_ws, size_t ws_size,
                              hipStream_t stream) {
  const float* X   = (const float*)d_in[0];
  const int*   tgt = (const int*)d_in[1];
  float*       out = (float*)d_out;

  char* ws = (char*)d_ws;
  unsigned short* Xb = (unsigned short*)ws;                       // 16 MiB
  float*    sq     = (float*)(ws + (size_t)N_PTS * DIM * 2);      // 16 KiB
  unsigned* far_b  = (unsigned*)(ws + (size_t)N_PTS * DIM * 2 + N_PTS * 4);
  unsigned* near_b = (unsigned*)(ws + (size_t)N_PTS * DIM * 2 + N_PTS * 8);

  prep_kernel<<<N_PTS, 256, 0, stream>>>(X, Xb, sq);
  init_kernel<<<(N_PTS + 255) / 256, 256, 0, stream>>>(far_b, near_b);
  dim3 grid(N_PTS / BN, N_PTS / BM);
  pairdist_kernel<<<grid, 256, 0, stream>>>(Xb, sq, tgt, far_b, near_b);
  finalize_kernel<<<1, 256, 0, stream>>>(far_b, near_b, out);
}

// Round 2
// 77.113 us; speedup vs baseline: 1.7266x; 1.7266x over previous
//
#include <hip/hip_runtime.h>
#include <hip/hip_bf16.h>
#include <cstdint>
#include <cstddef>

#define N_PTS 4096
#define DIM   2048
#define BM 128
#define BN 128
#define BK 32
#define NB (N_PTS / BM)   // 32 tile-rows; triangular grid = NB*(NB+1)/2 = 528

typedef __bf16 bf16x8 __attribute__((ext_vector_type(8)));
typedef float  f32x4  __attribute__((ext_vector_type(4)));
typedef unsigned short u16x8 __attribute__((ext_vector_type(8)));

__device__ __forceinline__ unsigned short f32_to_bf16_rne(float f) {
  unsigned u = __float_as_uint(f);
  u += 0x7fffu + ((u >> 16) & 1u);
  return (unsigned short)(u >> 16);
}

__device__ __forceinline__ void load_lds16(const void* g, void* l) {
  __builtin_amdgcn_global_load_lds(
      (const __attribute__((address_space(1))) void*)g,
      (__attribute__((address_space(3))) void*)l, 16, 0, 0);
}

// ---------------- prep: fp32 -> bf16 + exact fp32 row sum-of-squares + init far/near ---
__global__ __launch_bounds__(256) void prep_kernel(const float* __restrict__ X,
                                                   unsigned short* __restrict__ Xb,
                                                   float* __restrict__ sq,
                                                   unsigned* __restrict__ far_bits,
                                                   unsigned* __restrict__ near_bits) {
  const int row = blockIdx.x;
  const int t = threadIdx.x;
  const float4* xr = (const float4*)(X + (size_t)row * DIM);
  float4 v0 = xr[t * 2 + 0];
  float4 v1 = xr[t * 2 + 1];
  float s = v0.x * v0.x + v0.y * v0.y + v0.z * v0.z + v0.w * v0.w
          + v1.x * v1.x + v1.y * v1.y + v1.z * v1.z + v1.w * v1.w;
  u16x8 o;
  o[0] = f32_to_bf16_rne(v0.x); o[1] = f32_to_bf16_rne(v0.y);
  o[2] = f32_to_bf16_rne(v0.z); o[3] = f32_to_bf16_rne(v0.w);
  o[4] = f32_to_bf16_rne(v1.x); o[5] = f32_to_bf16_rne(v1.y);
  o[6] = f32_to_bf16_rne(v1.z); o[7] = f32_to_bf16_rne(v1.w);
  *(u16x8*)(Xb + (size_t)row * DIM + t * 8) = o;

  #pragma unroll
  for (int off = 32; off > 0; off >>= 1) s += __shfl_down(s, off, 64);
  __shared__ float wsum[4];
  const int lane = t & 63, w = t >> 6;
  if (lane == 0) wsum[w] = s;
  __syncthreads();
  if (t == 0) {
    sq[row] = wsum[0] + wsum[1] + wsum[2] + wsum[3];
    far_bits[row]  = 0u;           // 0.0f
    near_bits[row] = 0x7f800000u;  // +inf
  }
}

// ---------------- main fused pairwise-dist + dual (row+col) reduce, triangular grid ----
__global__ __launch_bounds__(256) void pairdist_kernel(
    const unsigned short* __restrict__ Xb, const float* __restrict__ sq,
    const int* __restrict__ tgt, unsigned* __restrict__ far_bits,
    unsigned* __restrict__ near_bits) {
  __shared__ unsigned short As[BM * BK];  // 8 KiB
  __shared__ unsigned short Bs[BN * BK];  // 8 KiB
  __shared__ float sq_r[BM], sq_c[BN];
  __shared__ int   t_r[BM],  t_c[BN];

  // decode triangular linear block id -> (bi, bj), bi <= bj
  int tl = blockIdx.x;
  int bi = (int)(((2 * NB + 1) - sqrtf((float)((2 * NB + 1) * (2 * NB + 1) - 8 * tl))) * 0.5f);
  while ((bi + 1) * (2 * NB + 1 - (bi + 1)) / 2 <= tl) bi++;
  while (bi * (2 * NB + 1 - bi) / 2 > tl) bi--;
  const int bj = bi + (tl - bi * (2 * NB + 1 - bi) / 2);
  const int i0 = bi * BM;
  const int j0 = bj * BN;

  const int tid  = threadIdx.x;
  const int lane = tid & 63;
  const int w    = tid >> 6;        // wave 0..3
  const int wr   = w >> 1;          // wave row 0..1
  const int wc   = w & 1;           // wave col 0..1

  if (tid < 128) { sq_r[tid] = sq[i0 + tid]; t_r[tid] = tgt[i0 + tid]; }
  else { int c = tid - 128; sq_c[c] = sq[j0 + c]; t_c[c] = tgt[j0 + c]; }

  f32x4 acc[4][4] = {};

  // staging geometry: per global_load_lds instr, a wave covers 16 rows x 64B
  const int srow = lane >> 2;          // row within 16-row chunk
  const int scol = (lane & 3) * 8;     // bf16 elems within BK row
  const int fr   = lane & 15;          // fragment row/col index
  const int kc   = (lane >> 4) * 8;    // fragment k offset (contiguous 8)

  for (int k0 = 0; k0 < DIM; k0 += BK) {
    const unsigned short* gA0 = Xb + (size_t)(i0 + w * 16 + srow) * DIM + k0 + scol;
    const unsigned short* gB0 = Xb + (size_t)(j0 + w * 16 + srow) * DIM + k0 + scol;
    load_lds16(gA0,            &As[(w * 16) * BK]);
    load_lds16(gA0 + 64 * DIM, &As[(64 + w * 16) * BK]);
    load_lds16(gB0,            &Bs[(w * 16) * BK]);
    load_lds16(gB0 + 64 * DIM, &Bs[(64 + w * 16) * BK]);
    __syncthreads();

    bf16x8 a[4], b[4];
    #pragma unroll
    for (int m = 0; m < 4; m++)
      a[m] = *(const bf16x8*)&As[(wr * 64 + m * 16 + fr) * BK + kc];
    #pragma unroll
    for (int n = 0; n < 4; n++)
      b[n] = *(const bf16x8*)&Bs[(wc * 64 + n * 16 + fr) * BK + kc];
    #pragma unroll
    for (int m = 0; m < 4; m++)
      #pragma unroll
      for (int n = 0; n < 4; n++)
        acc[m][n] = __builtin_amdgcn_mfma_f32_16x16x32_bf16(a[m], b[n], acc[m][n], 0, 0, 0);
    __syncthreads();
  }

  // ---- epilogue: reduce on d^2 (sqrt is monotone; sqrt once after reduce) ----
  const int hi = lane >> 4;
  const float INF = __builtin_inff();

  // per-lane column constants (col = fr within each 16-col fragment)
  float sqc_l[4]; int tc_l[4]; int gj_l[4];
  #pragma unroll
  for (int n = 0; n < 4; n++) {
    const int cl = wc * 64 + n * 16 + fr;
    sqc_l[n] = sq_c[cl]; tc_l[n] = t_c[cl]; gj_l[n] = j0 + cl;
  }

  float colf[4] = {0.f, 0.f, 0.f, 0.f};
  float coln[4] = {INF, INF, INF, INF};

  #pragma unroll
  for (int m = 0; m < 4; m++) {
    #pragma unroll
    for (int r = 0; r < 4; r++) {
      const int rl = wr * 64 + m * 16 + hi * 4 + r;
      const int gi = i0 + rl;
      const float sqr = sq_r[rl];
      const int   trw = t_r[rl];
      float fmx = 0.0f;
      float nmn = INF;
      #pragma unroll
      for (int n = 0; n < 4; n++) {
        const float g  = acc[m][n][r];
        const float d2 = fmaf(-2.0f, g, sqr + sqc_l[n]);
        if (trw == tc_l[n]) {
          fmx = fmaxf(fmx, d2);
          colf[n] = fmaxf(colf[n], d2);
          if (gi != gj_l[n]) {
            nmn = fminf(nmn, d2);
            coln[n] = fminf(coln[n], d2);
          }
        }
      }
      // row-side: reduce across the 16 cols held by this 16-lane group
      #pragma unroll
      for (int s = 1; s < 16; s <<= 1) {
        fmx = fmaxf(fmx, __shfl_xor(fmx, s, 64));
        nmn = fminf(nmn, __shfl_xor(nmn, s, 64));
      }
      if (fr == 0) {
        atomicMax(&far_bits[gi],  __float_as_uint(sqrtf(fmaxf(fmx, 1e-12f))));
        atomicMin(&near_bits[gi], __float_as_uint(sqrtf(fmaxf(nmn, 1e-12f))));
      }
    }
  }

  // col-side: each lane's colf/coln covers its 16 rows; combine the 4 hi-groups
  #pragma unroll
  for (int n = 0; n < 4; n++) {
    float f = colf[n], nn = coln[n];
    f  = fmaxf(f,  __shfl_xor(f,  16, 64));
    f  = fmaxf(f,  __shfl_xor(f,  32, 64));
    nn = fminf(nn, __shfl_xor(nn, 16, 64));
    nn = fminf(nn, __shfl_xor(nn, 32, 64));
    if (hi == 0) {
      atomicMax(&far_bits[gj_l[n]],  __float_as_uint(sqrtf(fmaxf(f,  1e-12f))));
      atomicMin(&near_bits[gj_l[n]], __float_as_uint(sqrtf(fmaxf(nn, 1e-12f))));
    }
  }
}

// ---------------- final deterministic reduction ----------------
__global__ __launch_bounds__(256) void finalize_kernel(
    const unsigned* __restrict__ far_bits, const unsigned* __restrict__ near_bits,
    float* __restrict__ out) {
  __shared__ float red[256];
  const int t = threadIdx.x;
  float s = 0.0f;
  for (int i = t; i < N_PTS; i += 256) {
    float fa = __uint_as_float(far_bits[i]);
    float ne = __uint_as_float(near_bits[i]);
    s += fmaxf(fa - ne, 0.0f);   // near=+inf -> -inf -> 0
  }
  red[t] = s;
  __syncthreads();
  for (int off = 128; off > 0; off >>= 1) {
    if (t < off) red[t] += red[t + off];
    __syncthreads();
  }
  if (t == 0) out[0] = red[0] / (float)N_PTS;
}

extern "C" void kernel_launch(void* const* d_in, const int* in_sizes, int n_in,
                              void* d_out, int out_size, void* d_ws, size_t ws_size,
                              hipStream_t stream) {
  const float* X   = (const float*)d_in[0];
  const int*   tgt = (const int*)d_in[1];
  float*       out = (float*)d_out;

  char* ws = (char*)d_ws;
  unsigned short* Xb = (unsigned short*)ws;                       // 16 MiB
  float*    sq     = (float*)(ws + (size_t)N_PTS * DIM * 2);      // 16 KiB
  unsigned* far_b  = (unsigned*)(ws + (size_t)N_PTS * DIM * 2 + N_PTS * 4);
  unsigned* near_b = (unsigned*)(ws + (size_t)N_PTS * DIM * 2 + N_PTS * 8);

  prep_kernel<<<N_PTS, 256, 0, stream>>>(X, Xb, sq, far_b, near_b);
  pairdist_kernel<<<NB * (NB + 1) / 2, 256, 0, stream>>>(Xb, sq, tgt, far_b, near_b);
  finalize_kernel<<<1, 256, 0, stream>>>(far_b, near_b, out);
}